// Round 11
// baseline (345.074 us; speedup 1.0000x reference)
//
#include <hip/hip_runtime.h>
#include <hip/hip_fp16.h>

#define N_NODES 100000
#define N_EDGES 800000
#define DIM 64
#define BN_EPS 1e-5f
#define LDX 68   // sX row stride (floats): 16B-aligned, 2-way banks (free)
#define EDGE_CAP 1600000

#define H2F_LO(u) __half2float(__ushort_as_half((unsigned short)((u) & 0xffff)))
#define H2F_HI(u) __half2float(__ushort_as_half((unsigned short)((u) >> 16)))

// ===========================================================================
// Merged: x (f32) -> xh (fp16) conversion + in-degree count + RANK capture.
// Round-10 profile: 42us, VALU 1.2%, HBM 17% -> the 800k divergent atomics
// dominate (~32 cy/atomic/CU serialized). This version issues 4 INDEPENDENT
// return-value atomics per thread (int4 dst load, int4 rank store) to test
// whether the atomic path is latency-bound (ILP helps) or issue-serialized.
// ===========================================================================
__global__ __launch_bounds__(256) void k_cvt_count(const float* __restrict__ x,
                                                   __half* __restrict__ xh,
                                                   const int* __restrict__ dst,
                                                   int* __restrict__ deg,
                                                   int* __restrict__ rank) {
    int idx = blockIdx.x * blockDim.x + threadIdx.x;
    if (idx < 1600000) {
        float4 v = ((const float4*)x)[idx];
        unsigned int u0 = __half_as_ushort(__float2half(v.x));
        unsigned int u1 = __half_as_ushort(__float2half(v.y));
        unsigned int u2 = __half_as_ushort(__float2half(v.z));
        unsigned int u3 = __half_as_ushort(__float2half(v.w));
        ((uint2*)xh)[idx] = make_uint2(u0 | (u1 << 16), u2 | (u3 << 16));
    }
    if (idx < 200000) {   // 4 edges/thread, 4 atomics in flight
        int4 d4 = ((const int4*)dst)[idx];
        int r0 = atomicAdd(&deg[d4.x], 1);
        int r1 = atomicAdd(&deg[d4.y], 1);
        int r2 = atomicAdd(&deg[d4.z], 1);
        int r3 = atomicAdd(&deg[d4.w], 1);
        ((int4*)rank)[idx] = make_int4(r0, r1, r2, r3);
    }
}

// ===========================================================================
// Merged scan + tail-weight algebra.
// Blocks 0..97: block-local scan of padded degrees + atomic global base;
// writes row_off, dinv. Block 98: W3p = W3@pW1, b3p = b3@pW1+pb1.
// ===========================================================================
__global__ __launch_bounds__(256) void k_scan_fuse(const int* __restrict__ deg,
                                                   int* __restrict__ row_off,
                                                   float* __restrict__ dinv,
                                                   int* __restrict__ gcount,
                                                   const float* __restrict__ W3,
                                                   const float* __restrict__ b3,
                                                   const float* __restrict__ pW1,
                                                   const float* __restrict__ pb1,
                                                   float* __restrict__ W3p,
                                                   float* __restrict__ b3p) {
    int tid = threadIdx.x;
    if (blockIdx.x == 98) {
        int c = tid & 63;
        int kbase = (tid >> 6) * 16;
        for (int k = kbase; k < kbase + 16; ++k) {
            float acc = 0.f;
#pragma unroll 8
            for (int j = 0; j < 64; ++j)
                acc = fmaf(W3[k * 64 + j], pW1[j * 64 + c], acc);
            W3p[k * 64 + c] = acc;
        }
        if (tid < 64) {
            float acc = pb1[c];
#pragma unroll 8
            for (int j = 0; j < 64; ++j)
                acc = fmaf(b3[j], pW1[j * 64 + c], acc);
            b3p[c] = acc;
        }
        return;
    }
    __shared__ int sdata[256];
    __shared__ int sbase;
    int base = blockIdx.x * 1024 + tid * 4;
    int4 d = make_int4(0, 0, 0, 0);
    int4 v = make_int4(0, 0, 0, 0);
    if (base < N_NODES) {
        d = *(const int4*)(deg + base);   // N % 4 == 0
        v.x = (d.x + 7) & ~7;
        v.y = (d.y + 7) & ~7;
        v.z = (d.z + 7) & ~7;
        v.w = (d.w + 7) & ~7;
    }
    int tsum = v.x + v.y + v.z + v.w;
    sdata[tid] = tsum;
    __syncthreads();
    for (int off = 1; off < 256; off <<= 1) {
        int t = (tid >= off) ? sdata[tid - off] : 0;
        __syncthreads();
        sdata[tid] += t;
        __syncthreads();
    }
    if (tid == 255) sbase = atomicAdd(gcount, sdata[255]);
    __syncthreads();
    if (base >= N_NODES) return;
    int excl = sdata[tid] - tsum + sbase;
    int4 o;
    o.x = excl;
    o.y = o.x + v.x;
    o.z = o.y + v.y;
    o.w = o.z + v.z;
    *(int4*)(row_off + base) = o;
    float4 di;
    di.x = rsqrtf((float)(d.x + 1));
    di.y = rsqrtf((float)(d.y + 1));
    di.z = rsqrtf((float)(d.z + 1));
    di.w = rsqrtf((float)(d.w + 1));
    *(float4*)(dinv + base) = di;
}

// ===========================================================================
// Atomic-free CSR build: pos = row_off[dst] + rank (captured in cvt_count).
// Packed int2 {src, weight}: single-load edge stream in aggregate (round 6
// proved src-only adds a dependent dinv gather per edge: +5us x3 aggregates).
// Weight = dinv[s]*dinv[d]: same single-rounded multiply as all prior rounds.
// ===========================================================================
__global__ __launch_bounds__(256) void k_build(const int* __restrict__ ei,
                                               const int* __restrict__ rank,
                                               const int* __restrict__ row_off,
                                               const float* __restrict__ dinv,
                                               int2* __restrict__ edges) {
    int idx = blockIdx.x * 256 + threadIdx.x;
    if (idx >= 200000) return;   // 4 edges/thread
    int4 s4 = ((const int4*)ei)[idx];
    int4 d4 = ((const int4*)(ei + N_EDGES))[idx];
    int4 r4 = ((const int4*)rank)[idx];
    edges[row_off[d4.x] + r4.x] = make_int2(s4.x, __float_as_int(dinv[s4.x] * dinv[d4.x]));
    edges[row_off[d4.y] + r4.y] = make_int2(s4.y, __float_as_int(dinv[s4.y] * dinv[d4.y]));
    edges[row_off[d4.z] + r4.z] = make_int2(s4.z, __float_as_int(dinv[s4.z] * dinv[d4.z]));
    edges[row_off[d4.w] + r4.w] = make_int2(s4.w, __float_as_int(dinv[s4.w] * dinv[d4.w]));
}

// ===========================================================================
// Aggregation v5 (round-10, proven): 8 nodes per wave, 8 lanes x uint4 per
// node — one gather covers 8 full 128B rows (64 lines in flight per 8-deep
// batch); explicit edge-prefetch pipeline removes edge-load latency from the
// gather chain. Clamped duplicate-tail loads with weight 0 -> single fp32
// accumulator per column in CSR order (bit-identical).
// ===========================================================================
__global__ __launch_bounds__(256) void k_aggregate(const __half* __restrict__ xin,
                                                   const int* __restrict__ row_off,
                                                   const int* __restrict__ deg,
                                                   const int2* __restrict__ edges,
                                                   const float* __restrict__ dinv,
                                                   __half* __restrict__ out) {
    int lane8 = threadIdx.x & 7;
    int node = blockIdx.x * 32 + (threadIdx.x >> 3);   // grid = 3125 exact
    float di = dinv[node];
    int beg = row_off[node];
    int len = deg[node];

    // self-loop term: 16 B per lane of this node's row
    uint4 us = ((const uint4*)(xin + (size_t)node * DIM))[lane8];
    float w0 = di * di;
    float acc[8];
    acc[0] = H2F_LO(us.x) * w0;
    acc[1] = H2F_HI(us.x) * w0;
    acc[2] = H2F_LO(us.y) * w0;
    acc[3] = H2F_HI(us.y) * w0;
    acc[4] = H2F_LO(us.z) * w0;
    acc[5] = H2F_HI(us.z) * w0;
    acc[6] = H2F_LO(us.w) * w0;
    acc[7] = H2F_HI(us.w) * w0;

    // wave-uniform max degree across the wave's 8 nodes
    int lenmax = len;
    lenmax = max(lenmax, __shfl_xor(lenmax, 8, 64));
    lenmax = max(lenmax, __shfl_xor(lenmax, 16, 64));
    lenmax = max(lenmax, __shfl_xor(lenmax, 32, 64));

    int lclamp = (len > 0) ? (len - 1) : 0;
    if (lenmax > 0) {
        int2 e[8];
#pragma unroll
        for (int u = 0; u < 8; ++u) {
            int jc = (u < lclamp) ? u : lclamp;
            e[u] = edges[beg + jc];
        }
        for (int i = 0; i < lenmax; i += 8) {
            int2 en[8];
            int inext = i + 8;
            if (inext < lenmax) {
#pragma unroll
                for (int u = 0; u < 8; ++u) {
                    int j = inext + u;
                    int jc = (j < lclamp) ? j : lclamp;
                    en[u] = edges[beg + jc];
                }
            } else {
#pragma unroll
                for (int u = 0; u < 8; ++u) en[u] = e[u];
            }
#pragma unroll
            for (int u = 0; u < 8; ++u) {
                int j = i + u;
                int s = ((unsigned)e[u].x < N_NODES) ? e[u].x : 0;  // safe if len==0
                float w = (j < len) ? __int_as_float(e[u].y) : 0.f;
                uint4 g = ((const uint4*)(xin + (size_t)s * DIM))[lane8];
                acc[0] = fmaf(w, H2F_LO(g.x), acc[0]);
                acc[1] = fmaf(w, H2F_HI(g.x), acc[1]);
                acc[2] = fmaf(w, H2F_LO(g.y), acc[2]);
                acc[3] = fmaf(w, H2F_HI(g.y), acc[3]);
                acc[4] = fmaf(w, H2F_LO(g.z), acc[4]);
                acc[5] = fmaf(w, H2F_HI(g.z), acc[5]);
                acc[6] = fmaf(w, H2F_LO(g.w), acc[6]);
                acc[7] = fmaf(w, H2F_HI(g.w), acc[7]);
            }
#pragma unroll
            for (int u = 0; u < 8; ++u) e[u] = en[u];
        }
    }

    uint4 p;
    p.x = __half_as_ushort(__float2half(acc[0])) | (__half_as_ushort(__float2half(acc[1])) << 16);
    p.y = __half_as_ushort(__float2half(acc[2])) | (__half_as_ushort(__float2half(acc[3])) << 16);
    p.z = __half_as_ushort(__float2half(acc[4])) | (__half_as_ushort(__float2half(acc[5])) << 16);
    p.w = __half_as_ushort(__float2half(acc[6])) | (__half_as_ushort(__float2half(acc[7])) << 16);
    ((uint4*)(out + (size_t)node * DIM))[lane8] = p;
}

// 64 FMAs of a 4-row x 4-col x 4-k outer-product step (sX stride = LDX)
#define GEMM_STEP(SX, SW)                                                      \
    {                                                                          \
        float4 a0 = *(const float4*)&SX[(r0 + 0) * LDX + k4 * 4];              \
        float4 a1 = *(const float4*)&SX[(r0 + 1) * LDX + k4 * 4];              \
        float4 a2 = *(const float4*)&SX[(r0 + 2) * LDX + k4 * 4];              \
        float4 a3 = *(const float4*)&SX[(r0 + 3) * LDX + k4 * 4];              \
        float4 b0 = *(const float4*)&SW[(k4 * 4 + 0) * 64 + c0];               \
        float4 b1 = *(const float4*)&SW[(k4 * 4 + 1) * 64 + c0];               \
        float4 b2 = *(const float4*)&SW[(k4 * 4 + 2) * 64 + c0];               \
        float4 b3 = *(const float4*)&SW[(k4 * 4 + 3) * 64 + c0];               \
        const float* ap[4] = {&a0.x, &a1.x, &a2.x, &a3.x};                     \
        _Pragma("unroll") for (int i = 0; i < 4; ++i) {                        \
            float x0 = ap[i][0], x1 = ap[i][1], x2 = ap[i][2], x3 = ap[i][3];  \
            acc[i][0] = fmaf(x0, b0.x, acc[i][0]);                             \
            acc[i][1] = fmaf(x0, b0.y, acc[i][1]);                             \
            acc[i][2] = fmaf(x0, b0.z, acc[i][2]);                             \
            acc[i][3] = fmaf(x0, b0.w, acc[i][3]);                             \
            acc[i][0] = fmaf(x1, b1.x, acc[i][0]);                             \
            acc[i][1] = fmaf(x1, b1.y, acc[i][1]);                             \
            acc[i][2] = fmaf(x1, b1.z, acc[i][2]);                             \
            acc[i][3] = fmaf(x1, b1.w, acc[i][3]);                             \
            acc[i][0] = fmaf(x2, b2.x, acc[i][0]);                             \
            acc[i][1] = fmaf(x2, b2.y, acc[i][1]);                             \
            acc[i][2] = fmaf(x2, b2.z, acc[i][2]);                             \
            acc[i][3] = fmaf(x2, b2.w, acc[i][3]);                             \
            acc[i][0] = fmaf(x3, b3.x, acc[i][0]);                             \
            acc[i][1] = fmaf(x3, b3.y, acc[i][1]);                             \
            acc[i][2] = fmaf(x3, b3.z, acc[i][2]);                             \
            acc[i][3] = fmaf(x3, b3.w, acc[i][3]);                             \
        }                                                                      \
    }

// stage one 64-row fp16 tile into fp32 LDS (thread r=tid>>2, q=tid&3)
#define STAGE_H2F(SRCPTR, SXPTR)                                               \
    {                                                                          \
        int r = tid >> 2;                                                      \
        int q = tid & 3;                                                       \
        int row = row0 + r;                                                    \
        float4* dst = (float4*)(SXPTR + r * LDX);                              \
        if (row < N_NODES) {                                                   \
            const uint2* src = (const uint2*)(SRCPTR + (size_t)row * DIM);     \
            _Pragma("unroll") for (int m = 0; m < 4; ++m) {                    \
                uint2 u = src[q + m * 4];                                      \
                float4 f;                                                      \
                f.x = H2F_LO(u.x);                                             \
                f.y = H2F_HI(u.x);                                             \
                f.z = H2F_LO(u.y);                                             \
                f.w = H2F_HI(u.y);                                             \
                dst[q + m * 4] = f;                                            \
            }                                                                  \
        } else {                                                               \
            float4 z = make_float4(0.f, 0.f, 0.f, 0.f);                        \
            _Pragma("unroll") for (int m = 0; m < 4; ++m) dst[q + m * 4] = z;  \
        }                                                                      \
    }

// ===========================================================================
// Register-tiled GEMM + BN + ReLU: fp16 in, fp16 out, fp32 math.
// ===========================================================================
__global__ __launch_bounds__(256) void k_gemm_bn_h(const __half* __restrict__ xin,
                                                   const float* __restrict__ W,
                                                   const float* __restrict__ bias,
                                                   const float* __restrict__ bng,
                                                   const float* __restrict__ bnb,
                                                   const float* __restrict__ bnm,
                                                   const float* __restrict__ bnv,
                                                   __half* __restrict__ out) {
    __shared__ float sW[4096];
    __shared__ float sX[64 * LDX];
    int tid = threadIdx.x;
    int row0 = blockIdx.x * 64;

    for (int i = tid; i < 1024; i += 256)
        ((float4*)sW)[i] = ((const float4*)W)[i];
    STAGE_H2F(xin, sX)
    __syncthreads();

    int cq = tid & 15, rq = tid >> 4;
    int c0 = cq * 4, r0 = rq * 4;
    float acc[4][4];
#pragma unroll
    for (int i = 0; i < 4; ++i)
#pragma unroll
        for (int j = 0; j < 4; ++j) acc[i][j] = 0.f;

#pragma unroll 4
    for (int k4 = 0; k4 < 16; ++k4) GEMM_STEP(sX, sW)

    float4 bv = *(const float4*)&bias[c0];
    float4 g = *(const float4*)&bng[c0];
    float4 bb = *(const float4*)&bnb[c0];
    float4 m = *(const float4*)&bnm[c0];
    float4 vv = *(const float4*)&bnv[c0];
    float A0 = g.x * rsqrtf(vv.x + BN_EPS);
    float A1 = g.y * rsqrtf(vv.y + BN_EPS);
    float A2 = g.z * rsqrtf(vv.z + BN_EPS);
    float A3 = g.w * rsqrtf(vv.w + BN_EPS);
    float B0 = (bv.x - m.x) * A0 + bb.x;
    float B1 = (bv.y - m.y) * A1 + bb.y;
    float B2 = (bv.z - m.z) * A2 + bb.z;
    float B3 = (bv.w - m.w) * A3 + bb.w;
#pragma unroll
    for (int i = 0; i < 4; ++i) {
        int row = row0 + r0 + i;
        if (row >= N_NODES) break;
        unsigned int u0 = __half_as_ushort(__float2half(fmaxf(0.f, fmaf(acc[i][0], A0, B0))));
        unsigned int u1 = __half_as_ushort(__float2half(fmaxf(0.f, fmaf(acc[i][1], A1, B1))));
        unsigned int u2 = __half_as_ushort(__float2half(fmaxf(0.f, fmaf(acc[i][2], A2, B2))));
        unsigned int u3 = __half_as_ushort(__float2half(fmaxf(0.f, fmaf(acc[i][3], A3, B3))));
        *(uint2*)(out + (size_t)row * DIM + c0) = make_uint2(u0 | (u1 << 16), u2 | (u3 << 16));
    }
}

// ===========================================================================
// Tail: out = tanh(x @ W3p + b3p) @ pW2 + pb2; fp16 in, fp32 out.
// ===========================================================================
__global__ __launch_bounds__(256) void k_tail(const __half* __restrict__ xin,
                                              const float* __restrict__ W3p,
                                              const float* __restrict__ b3p,
                                              const float* __restrict__ pW2,
                                              const float* __restrict__ pb2,
                                              float* __restrict__ out) {
    __shared__ float sW1[4096];
    __shared__ float sW2[4096];
    __shared__ float sX[64 * LDX];
    int tid = threadIdx.x;
    int row0 = blockIdx.x * 64;

    for (int i = tid; i < 1024; i += 256) {
        ((float4*)sW1)[i] = ((const float4*)W3p)[i];
        ((float4*)sW2)[i] = ((const float4*)pW2)[i];
    }
    STAGE_H2F(xin, sX)
    __syncthreads();

    int cq = tid & 15, rq = tid >> 4;
    int c0 = cq * 4, r0 = rq * 4;
    float acc[4][4];

    // ---- GEMM 1: sX @ W3p ----
#pragma unroll
    for (int i = 0; i < 4; ++i)
#pragma unroll
        for (int j = 0; j < 4; ++j) acc[i][j] = 0.f;
#pragma unroll 4
    for (int k4 = 0; k4 < 16; ++k4) GEMM_STEP(sX, sW1)
    __syncthreads();

    {
        float4 bv = *(const float4*)&b3p[c0];
#pragma unroll
        for (int i = 0; i < 4; ++i) {
            float4 h;
            h.x = tanhf(acc[i][0] + bv.x);
            h.y = tanhf(acc[i][1] + bv.y);
            h.z = tanhf(acc[i][2] + bv.z);
            h.w = tanhf(acc[i][3] + bv.w);
            *(float4*)&sX[(r0 + i) * LDX + c0] = h;
        }
    }
    __syncthreads();

    // ---- GEMM 2: sX @ pW2 ----
#pragma unroll
    for (int i = 0; i < 4; ++i)
#pragma unroll
        for (int j = 0; j < 4; ++j) acc[i][j] = 0.f;
#pragma unroll 4
    for (int k4 = 0; k4 < 16; ++k4) GEMM_STEP(sX, sW2)

    float4 bv = *(const float4*)&pb2[c0];
#pragma unroll
    for (int i = 0; i < 4; ++i) {
        int row = row0 + r0 + i;
        if (row >= N_NODES) break;
        float4 o;
        o.x = acc[i][0] + bv.x;
        o.y = acc[i][1] + bv.y;
        o.z = acc[i][2] + bv.z;
        o.w = acc[i][3] + bv.w;
        *(float4*)(out + (size_t)row * DIM + c0) = o;
    }
}

// ===========================================================================
extern "C" void kernel_launch(void* const* d_in, const int* in_sizes, int n_in,
                              void* d_out, int out_size, void* d_ws, size_t ws_size,
                              hipStream_t stream) {
    const float* x     = (const float*)d_in[0];
    const int*   ei    = (const int*)d_in[1];
    const float* W1    = (const float*)d_in[2];
    const float* b1    = (const float*)d_in[3];
    const float* W2    = (const float*)d_in[4];
    const float* b2    = (const float*)d_in[5];
    const float* W3    = (const float*)d_in[6];
    const float* b3    = (const float*)d_in[7];
    const float* bn1_g = (const float*)d_in[8];
    const float* bn1_b = (const float*)d_in[9];
    const float* bn1_m = (const float*)d_in[10];
    const float* bn1_v = (const float*)d_in[11];
    const float* bn2_g = (const float*)d_in[12];
    const float* bn2_b = (const float*)d_in[13];
    const float* bn2_m = (const float*)d_in[14];
    const float* bn2_v = (const float*)d_in[15];
    const float* pW1   = (const float*)d_in[16];
    const float* pb1   = (const float*)d_in[17];
    const float* pW2   = (const float*)d_in[18];
    const float* pb2   = (const float*)d_in[19];
    float* out = (float*)d_out;

    // deg and gcount adjacent -> ONE small memset zeroes both. row_off/rank/
    // edges fully written by producers; edge pad slots never read (clamped).
    char* ws = (char*)d_ws;
    int*    deg     = (int*)ws;                      ws += 100352 * 4;
    int*    gcount  = (int*)ws;                      ws += 4 * 4;
    int*    row_off = (int*)ws;                      ws += 100352 * 4;
    int*    rank    = (int*)ws;                      ws += (size_t)N_EDGES * 4;
    int2*   edges   = (int2*)ws;                     ws += (size_t)EDGE_CAP * 8;
    float*  dinv    = (float*)ws;                    ws += 100352 * 4;
    float*  W3p     = (float*)ws;                    ws += 4096 * 4;
    float*  b3p     = (float*)ws;                    ws += 64 * 4;
    __half* xh      = (__half*)ws;                   ws += (size_t)N_NODES * DIM * 2;
    __half* hbuf    = (__half*)ws;                   ws += (size_t)N_NODES * DIM * 2;
    __half* abuf    = (__half*)ws;                   ws += (size_t)N_NODES * DIM * 2;

    const int blk = 256;
    int gCvt   = 6250;                           // 1.6M cvt chunks; 200k edge-quads
    int gBuild = 782;                            // 200000 int4 edge-quads
    int gAgg   = N_NODES / 32;                   // 3125 (32 nodes/block)
    int gTile  = (N_NODES + 63) / 64;            // 1563

    hipMemsetAsync(deg, 0, (size_t)(100352 + 4) * 4, stream);
    k_cvt_count<<<gCvt, blk, 0, stream>>>(x, xh, ei + N_EDGES, deg, rank);
    k_scan_fuse<<<99, blk, 0, stream>>>(deg, row_off, dinv, gcount,
                                        W3, b3, pW1, pb1, W3p, b3p);
    k_build<<<gBuild, blk, 0, stream>>>(ei, rank, row_off, dinv, edges);

    // ---- layer 1 ----
    k_aggregate<<<gAgg, blk, 0, stream>>>(xh, row_off, deg, edges, dinv, abuf);
    k_gemm_bn_h<<<gTile, blk, 0, stream>>>(abuf, W1, b1, bn1_g, bn1_b, bn1_m, bn1_v, hbuf);

    // ---- layer 2 ----
    k_aggregate<<<gAgg, blk, 0, stream>>>(hbuf, row_off, deg, edges, dinv, abuf);
    k_gemm_bn_h<<<gTile, blk, 0, stream>>>(abuf, W2, b2, bn2_g, bn2_b, bn2_m, bn2_v, hbuf);

    // ---- layer 3 + fused predictor ----
    k_aggregate<<<gAgg, blk, 0, stream>>>(hbuf, row_off, deg, edges, dinv, abuf);
    k_tail<<<gTile, blk, 0, stream>>>(abuf, W3p, b3p, pW2, pb2, out);
}

// Round 13
// 338.792 us; speedup vs baseline: 1.0185x; 1.0185x over previous
//
#include <hip/hip_runtime.h>
#include <hip/hip_fp16.h>

#define N_NODES 100000
#define N_EDGES 800000
#define DIM 64
#define BN_EPS 1e-5f
#define LDX 68   // sX row stride (floats): 16B-aligned, 2-way banks (free)
#define EDGE_CAP 1600000

#define H2F_LO(u) __half2float(__ushort_as_half((unsigned short)((u) & 0xffff)))
#define H2F_HI(u) __half2float(__ushort_as_half((unsigned short)((u) >> 16)))

// ===========================================================================
// Merged: x (f32) -> xh (fp16, LINEAR 128B rows) conversion + in-degree count
// + RANK capture. The deg atomicAdd's return value is the edge's rank within
// its dst segment. (Round 11 proved the atomic path is per-CU
// issue-serialized: 4-wide atomic ILP was neutral. ~42us is the wall here.)
// ===========================================================================
__global__ __launch_bounds__(256) void k_cvt_count(const float* __restrict__ x,
                                                   __half* __restrict__ xh,
                                                   const int* __restrict__ dst,
                                                   int* __restrict__ deg,
                                                   int* __restrict__ rank) {
    int idx = blockIdx.x * blockDim.x + threadIdx.x;
    if (idx < 1600000) {
        float4 v = ((const float4*)x)[idx];
        unsigned int u0 = __half_as_ushort(__float2half(v.x));
        unsigned int u1 = __half_as_ushort(__float2half(v.y));
        unsigned int u2 = __half_as_ushort(__float2half(v.z));
        unsigned int u3 = __half_as_ushort(__float2half(v.w));
        ((uint2*)xh)[idx] = make_uint2(u0 | (u1 << 16), u2 | (u3 << 16));
    }
    if (idx < N_EDGES) rank[idx] = atomicAdd(&deg[dst[idx]], 1);
}

// ===========================================================================
// Merged scan + tail-weight algebra.
// Blocks 0..97: block-local scan of padded degrees + atomic global base;
// writes row_off, dinv. Block 98: W3p = W3@pW1, b3p = b3@pW1+pb1.
// ===========================================================================
__global__ __launch_bounds__(256) void k_scan_fuse(const int* __restrict__ deg,
                                                   int* __restrict__ row_off,
                                                   float* __restrict__ dinv,
                                                   int* __restrict__ gcount,
                                                   const float* __restrict__ W3,
                                                   const float* __restrict__ b3,
                                                   const float* __restrict__ pW1,
                                                   const float* __restrict__ pb1,
                                                   float* __restrict__ W3p,
                                                   float* __restrict__ b3p) {
    int tid = threadIdx.x;
    if (blockIdx.x == 98) {
        int c = tid & 63;
        int kbase = (tid >> 6) * 16;
        for (int k = kbase; k < kbase + 16; ++k) {
            float acc = 0.f;
#pragma unroll 8
            for (int j = 0; j < 64; ++j)
                acc = fmaf(W3[k * 64 + j], pW1[j * 64 + c], acc);
            W3p[k * 64 + c] = acc;
        }
        if (tid < 64) {
            float acc = pb1[c];
#pragma unroll 8
            for (int j = 0; j < 64; ++j)
                acc = fmaf(b3[j], pW1[j * 64 + c], acc);
            b3p[c] = acc;
        }
        return;
    }
    __shared__ int sdata[256];
    __shared__ int sbase;
    int base = blockIdx.x * 1024 + tid * 4;
    int4 d = make_int4(0, 0, 0, 0);
    int4 v = make_int4(0, 0, 0, 0);
    if (base < N_NODES) {
        d = *(const int4*)(deg + base);   // N % 4 == 0
        v.x = (d.x + 7) & ~7;
        v.y = (d.y + 7) & ~7;
        v.z = (d.z + 7) & ~7;
        v.w = (d.w + 7) & ~7;
    }
    int tsum = v.x + v.y + v.z + v.w;
    sdata[tid] = tsum;
    __syncthreads();
    for (int off = 1; off < 256; off <<= 1) {
        int t = (tid >= off) ? sdata[tid - off] : 0;
        __syncthreads();
        sdata[tid] += t;
        __syncthreads();
    }
    if (tid == 255) sbase = atomicAdd(gcount, sdata[255]);
    __syncthreads();
    if (base >= N_NODES) return;
    int excl = sdata[tid] - tsum + sbase;
    int4 o;
    o.x = excl;
    o.y = o.x + v.x;
    o.z = o.y + v.y;
    o.w = o.z + v.z;
    *(int4*)(row_off + base) = o;
    float4 di;
    di.x = rsqrtf((float)(d.x + 1));
    di.y = rsqrtf((float)(d.y + 1));
    di.z = rsqrtf((float)(d.z + 1));
    di.w = rsqrtf((float)(d.w + 1));
    *(float4*)(dinv + base) = di;
}

// ===========================================================================
// Atomic-free CSR build: pos = row_off[dst] + rank (captured in cvt_count).
// Packed int2 {src, weight}: single-load edge stream in aggregate (round 6
// proved src-only adds a dependent dinv gather per edge: +5us x3 aggregates).
// Weight = dinv[s]*dinv[d]: same single-rounded multiply as all prior rounds.
// ===========================================================================
__global__ __launch_bounds__(256) void k_build(const int* __restrict__ ei,
                                               const int* __restrict__ rank,
                                               const int* __restrict__ row_off,
                                               const float* __restrict__ dinv,
                                               int2* __restrict__ edges) {
    int idx = blockIdx.x * 256 + threadIdx.x;
    if (idx >= 200000) return;   // 4 edges/thread
    int4 s4 = ((const int4*)ei)[idx];
    int4 d4 = ((const int4*)(ei + N_EDGES))[idx];
    int4 r4 = ((const int4*)rank)[idx];
    edges[row_off[d4.x] + r4.x] = make_int2(s4.x, __float_as_int(dinv[s4.x] * dinv[d4.x]));
    edges[row_off[d4.y] + r4.y] = make_int2(s4.y, __float_as_int(dinv[s4.y] * dinv[d4.y]));
    edges[row_off[d4.z] + r4.z] = make_int2(s4.z, __float_as_int(dinv[s4.z] * dinv[d4.z]));
    edges[row_off[d4.w] + r4.w] = make_int2(s4.w, __float_as_int(dinv[s4.w] * dinv[d4.w]));
}

// ===========================================================================
// Aggregation v5 (round-10, proven): 8 nodes per wave, 8 lanes x uint4 per
// node — one gather covers 8 full 128B rows (64 lines in flight per 8-deep
// batch); explicit edge-prefetch pipeline removes edge-load latency from the
// gather chain. Clamped duplicate-tail loads with weight 0 -> single fp32
// accumulator per column in CSR order (bit-identical).
// ===========================================================================
__global__ __launch_bounds__(256) void k_aggregate(const __half* __restrict__ xin,
                                                   const int* __restrict__ row_off,
                                                   const int* __restrict__ deg,
                                                   const int2* __restrict__ edges,
                                                   const float* __restrict__ dinv,
                                                   __half* __restrict__ out) {
    int lane8 = threadIdx.x & 7;
    int node = blockIdx.x * 32 + (threadIdx.x >> 3);   // grid = 3125 exact
    float di = dinv[node];
    int beg = row_off[node];
    int len = deg[node];

    // self-loop term: 16 B per lane of this node's row
    uint4 us = ((const uint4*)(xin + (size_t)node * DIM))[lane8];
    float w0 = di * di;
    float acc[8];
    acc[0] = H2F_LO(us.x) * w0;
    acc[1] = H2F_HI(us.x) * w0;
    acc[2] = H2F_LO(us.y) * w0;
    acc[3] = H2F_HI(us.y) * w0;
    acc[4] = H2F_LO(us.z) * w0;
    acc[5] = H2F_HI(us.z) * w0;
    acc[6] = H2F_LO(us.w) * w0;
    acc[7] = H2F_HI(us.w) * w0;

    // wave-uniform max degree across the wave's 8 nodes
    int lenmax = len;
    lenmax = max(lenmax, __shfl_xor(lenmax, 8, 64));
    lenmax = max(lenmax, __shfl_xor(lenmax, 16, 64));
    lenmax = max(lenmax, __shfl_xor(lenmax, 32, 64));

    int lclamp = (len > 0) ? (len - 1) : 0;
    if (lenmax > 0) {
        int2 e[8];
#pragma unroll
        for (int u = 0; u < 8; ++u) {
            int jc = (u < lclamp) ? u : lclamp;
            e[u] = edges[beg + jc];
        }
        for (int i = 0; i < lenmax; i += 8) {
            int2 en[8];
            int inext = i + 8;
            if (inext < lenmax) {
#pragma unroll
                for (int u = 0; u < 8; ++u) {
                    int j = inext + u;
                    int jc = (j < lclamp) ? j : lclamp;
                    en[u] = edges[beg + jc];
                }
            } else {
#pragma unroll
                for (int u = 0; u < 8; ++u) en[u] = e[u];
            }
#pragma unroll
            for (int u = 0; u < 8; ++u) {
                int j = i + u;
                int s = ((unsigned)e[u].x < N_NODES) ? e[u].x : 0;  // safe if len==0
                float w = (j < len) ? __int_as_float(e[u].y) : 0.f;
                uint4 g = ((const uint4*)(xin + (size_t)s * DIM))[lane8];
                acc[0] = fmaf(w, H2F_LO(g.x), acc[0]);
                acc[1] = fmaf(w, H2F_HI(g.x), acc[1]);
                acc[2] = fmaf(w, H2F_LO(g.y), acc[2]);
                acc[3] = fmaf(w, H2F_HI(g.y), acc[3]);
                acc[4] = fmaf(w, H2F_LO(g.z), acc[4]);
                acc[5] = fmaf(w, H2F_HI(g.z), acc[5]);
                acc[6] = fmaf(w, H2F_LO(g.w), acc[6]);
                acc[7] = fmaf(w, H2F_HI(g.w), acc[7]);
            }
#pragma unroll
            for (int u = 0; u < 8; ++u) e[u] = en[u];
        }
    }

    uint4 p;
    p.x = __half_as_ushort(__float2half(acc[0])) | (__half_as_ushort(__float2half(acc[1])) << 16);
    p.y = __half_as_ushort(__float2half(acc[2])) | (__half_as_ushort(__float2half(acc[3])) << 16);
    p.z = __half_as_ushort(__float2half(acc[4])) | (__half_as_ushort(__float2half(acc[5])) << 16);
    p.w = __half_as_ushort(__float2half(acc[6])) | (__half_as_ushort(__float2half(acc[7])) << 16);
    ((uint4*)(out + (size_t)node * DIM))[lane8] = p;
}

// 64 FMAs of a 4-row x 4-col x 4-k outer-product step (sX stride = LDX)
#define GEMM_STEP(SX, SW)                                                      \
    {                                                                          \
        float4 a0 = *(const float4*)&SX[(r0 + 0) * LDX + k4 * 4];              \
        float4 a1 = *(const float4*)&SX[(r0 + 1) * LDX + k4 * 4];              \
        float4 a2 = *(const float4*)&SX[(r0 + 2) * LDX + k4 * 4];              \
        float4 a3 = *(const float4*)&SX[(r0 + 3) * LDX + k4 * 4];              \
        float4 b0 = *(const float4*)&SW[(k4 * 4 + 0) * 64 + c0];               \
        float4 b1 = *(const float4*)&SW[(k4 * 4 + 1) * 64 + c0];               \
        float4 b2 = *(const float4*)&SW[(k4 * 4 + 2) * 64 + c0];               \
        float4 b3 = *(const float4*)&SW[(k4 * 4 + 3) * 64 + c0];               \
        const float* ap[4] = {&a0.x, &a1.x, &a2.x, &a3.x};                     \
        _Pragma("unroll") for (int i = 0; i < 4; ++i) {                        \
            float x0 = ap[i][0], x1 = ap[i][1], x2 = ap[i][2], x3 = ap[i][3];  \
            acc[i][0] = fmaf(x0, b0.x, acc[i][0]);                             \
            acc[i][1] = fmaf(x0, b0.y, acc[i][1]);                             \
            acc[i][2] = fmaf(x0, b0.z, acc[i][2]);                             \
            acc[i][3] = fmaf(x0, b0.w, acc[i][3]);                             \
            acc[i][0] = fmaf(x1, b1.x, acc[i][0]);                             \
            acc[i][1] = fmaf(x1, b1.y, acc[i][1]);                             \
            acc[i][2] = fmaf(x1, b1.z, acc[i][2]);                             \
            acc[i][3] = fmaf(x1, b1.w, acc[i][3]);                             \
            acc[i][0] = fmaf(x2, b2.x, acc[i][0]);                             \
            acc[i][1] = fmaf(x2, b2.y, acc[i][1]);                             \
            acc[i][2] = fmaf(x2, b2.z, acc[i][2]);                             \
            acc[i][3] = fmaf(x2, b2.w, acc[i][3]);                             \
            acc[i][0] = fmaf(x3, b3.x, acc[i][0]);                             \
            acc[i][1] = fmaf(x3, b3.y, acc[i][1]);                             \
            acc[i][2] = fmaf(x3, b3.z, acc[i][2]);                             \
            acc[i][3] = fmaf(x3, b3.w, acc[i][3]);                             \
        }                                                                      \
    }

// stage one 64-row fp16 tile into fp32 LDS (thread r=tid>>2, q=tid&3)
#define STAGE_H2F(SRCPTR, SXPTR)                                               \
    {                                                                          \
        int r = tid >> 2;                                                      \
        int q = tid & 3;                                                       \
        int row = row0 + r;                                                    \
        float4* dst = (float4*)(SXPTR + r * LDX);                              \
        if (row < N_NODES) {                                                   \
            const uint2* src = (const uint2*)(SRCPTR + (size_t)row * DIM);     \
            _Pragma("unroll") for (int m = 0; m < 4; ++m) {                    \
                uint2 u = src[q + m * 4];                                      \
                float4 f;                                                      \
                f.x = H2F_LO(u.x);                                             \
                f.y = H2F_HI(u.x);                                             \
                f.z = H2F_LO(u.y);                                             \
                f.w = H2F_HI(u.y);                                             \
                dst[q + m * 4] = f;                                            \
            }                                                                  \
        } else {                                                               \
            float4 z = make_float4(0.f, 0.f, 0.f, 0.f);                        \
            _Pragma("unroll") for (int m = 0; m < 4; ++m) dst[q + m * 4] = z;  \
        }                                                                      \
    }

// ===========================================================================
// Register-tiled GEMM + BN + ReLU: fp16 in, fp16 out, fp32 math.
// ===========================================================================
__global__ __launch_bounds__(256) void k_gemm_bn_h(const __half* __restrict__ xin,
                                                   const float* __restrict__ W,
                                                   const float* __restrict__ bias,
                                                   const float* __restrict__ bng,
                                                   const float* __restrict__ bnb,
                                                   const float* __restrict__ bnm,
                                                   const float* __restrict__ bnv,
                                                   __half* __restrict__ out) {
    __shared__ float sW[4096];
    __shared__ float sX[64 * LDX];
    int tid = threadIdx.x;
    int row0 = blockIdx.x * 64;

    for (int i = tid; i < 1024; i += 256)
        ((float4*)sW)[i] = ((const float4*)W)[i];
    STAGE_H2F(xin, sX)
    __syncthreads();

    int cq = tid & 15, rq = tid >> 4;
    int c0 = cq * 4, r0 = rq * 4;
    float acc[4][4];
#pragma unroll
    for (int i = 0; i < 4; ++i)
#pragma unroll
        for (int j = 0; j < 4; ++j) acc[i][j] = 0.f;

#pragma unroll 4
    for (int k4 = 0; k4 < 16; ++k4) GEMM_STEP(sX, sW)

    float4 bv = *(const float4*)&bias[c0];
    float4 g = *(const float4*)&bng[c0];
    float4 bb = *(const float4*)&bnb[c0];
    float4 m = *(const float4*)&bnm[c0];
    float4 vv = *(const float4*)&bnv[c0];
    float A0 = g.x * rsqrtf(vv.x + BN_EPS);
    float A1 = g.y * rsqrtf(vv.y + BN_EPS);
    float A2 = g.z * rsqrtf(vv.z + BN_EPS);
    float A3 = g.w * rsqrtf(vv.w + BN_EPS);
    float B0 = (bv.x - m.x) * A0 + bb.x;
    float B1 = (bv.y - m.y) * A1 + bb.y;
    float B2 = (bv.z - m.z) * A2 + bb.z;
    float B3 = (bv.w - m.w) * A3 + bb.w;
#pragma unroll
    for (int i = 0; i < 4; ++i) {
        int row = row0 + r0 + i;
        if (row >= N_NODES) break;
        unsigned int u0 = __half_as_ushort(__float2half(fmaxf(0.f, fmaf(acc[i][0], A0, B0))));
        unsigned int u1 = __half_as_ushort(__float2half(fmaxf(0.f, fmaf(acc[i][1], A1, B1))));
        unsigned int u2 = __half_as_ushort(__float2half(fmaxf(0.f, fmaf(acc[i][2], A2, B2))));
        unsigned int u3 = __half_as_ushort(__float2half(fmaxf(0.f, fmaf(acc[i][3], A3, B3))));
        *(uint2*)(out + (size_t)row * DIM + c0) = make_uint2(u0 | (u1 << 16), u2 | (u3 << 16));
    }
}

// ===========================================================================
// Tail: out = tanh(x @ W3p + b3p) @ pW2 + pb2; fp16 in, fp32 out.
// ===========================================================================
__global__ __launch_bounds__(256) void k_tail(const __half* __restrict__ xin,
                                              const float* __restrict__ W3p,
                                              const float* __restrict__ b3p,
                                              const float* __restrict__ pW2,
                                              const float* __restrict__ pb2,
                                              float* __restrict__ out) {
    __shared__ float sW1[4096];
    __shared__ float sW2[4096];
    __shared__ float sX[64 * LDX];
    int tid = threadIdx.x;
    int row0 = blockIdx.x * 64;

    for (int i = tid; i < 1024; i += 256) {
        ((float4*)sW1)[i] = ((const float4*)W3p)[i];
        ((float4*)sW2)[i] = ((const float4*)pW2)[i];
    }
    STAGE_H2F(xin, sX)
    __syncthreads();

    int cq = tid & 15, rq = tid >> 4;
    int c0 = cq * 4, r0 = rq * 4;
    float acc[4][4];

    // ---- GEMM 1: sX @ W3p ----
#pragma unroll
    for (int i = 0; i < 4; ++i)
#pragma unroll
        for (int j = 0; j < 4; ++j) acc[i][j] = 0.f;
#pragma unroll 4
    for (int k4 = 0; k4 < 16; ++k4) GEMM_STEP(sX, sW1)
    __syncthreads();

    {
        float4 bv = *(const float4*)&b3p[c0];
#pragma unroll
        for (int i = 0; i < 4; ++i) {
            float4 h;
            h.x = tanhf(acc[i][0] + bv.x);
            h.y = tanhf(acc[i][1] + bv.y);
            h.z = tanhf(acc[i][2] + bv.z);
            h.w = tanhf(acc[i][3] + bv.w);
            *(float4*)&sX[(r0 + i) * LDX + c0] = h;
        }
    }
    __syncthreads();

    // ---- GEMM 2: sX @ pW2 ----
#pragma unroll
    for (int i = 0; i < 4; ++i)
#pragma unroll
        for (int j = 0; j < 4; ++j) acc[i][j] = 0.f;
#pragma unroll 4
    for (int k4 = 0; k4 < 16; ++k4) GEMM_STEP(sX, sW2)

    float4 bv = *(const float4*)&pb2[c0];
#pragma unroll
    for (int i = 0; i < 4; ++i) {
        int row = row0 + r0 + i;
        if (row >= N_NODES) break;
        float4 o;
        o.x = acc[i][0] + bv.x;
        o.y = acc[i][1] + bv.y;
        o.z = acc[i][2] + bv.z;
        o.w = acc[i][3] + bv.w;
        *(float4*)(out + (size_t)row * DIM + c0) = o;
    }
}

// ===========================================================================
extern "C" void kernel_launch(void* const* d_in, const int* in_sizes, int n_in,
                              void* d_out, int out_size, void* d_ws, size_t ws_size,
                              hipStream_t stream) {
    const float* x     = (const float*)d_in[0];
    const int*   ei    = (const int*)d_in[1];
    const float* W1    = (const float*)d_in[2];
    const float* b1    = (const float*)d_in[3];
    const float* W2    = (const float*)d_in[4];
    const float* b2    = (const float*)d_in[5];
    const float* W3    = (const float*)d_in[6];
    const float* b3    = (const float*)d_in[7];
    const float* bn1_g = (const float*)d_in[8];
    const float* bn1_b = (const float*)d_in[9];
    const float* bn1_m = (const float*)d_in[10];
    const float* bn1_v = (const float*)d_in[11];
    const float* bn2_g = (const float*)d_in[12];
    const float* bn2_b = (const float*)d_in[13];
    const float* bn2_m = (const float*)d_in[14];
    const float* bn2_v = (const float*)d_in[15];
    const float* pW1   = (const float*)d_in[16];
    const float* pb1   = (const float*)d_in[17];
    const float* pW2   = (const float*)d_in[18];
    const float* pb2   = (const float*)d_in[19];
    float* out = (float*)d_out;

    // deg and gcount adjacent -> ONE small memset zeroes both. row_off/rank/
    // edges fully written by producers; edge pad slots never read (clamped).
    char* ws = (char*)d_ws;
    int*    deg     = (int*)ws;                      ws += 100352 * 4;
    int*    gcount  = (int*)ws;                      ws += 4 * 4;
    int*    row_off = (int*)ws;                      ws += 100352 * 4;
    int*    rank    = (int*)ws;                      ws += (size_t)N_EDGES * 4;
    int2*   edges   = (int2*)ws;                     ws += (size_t)EDGE_CAP * 8;
    float*  dinv    = (float*)ws;                    ws += 100352 * 4;
    float*  W3p     = (float*)ws;                    ws += 4096 * 4;
    float*  b3p     = (float*)ws;                    ws += 64 * 4;
    __half* xh      = (__half*)ws;                   ws += (size_t)N_NODES * DIM * 2;
    __half* hbuf    = (__half*)ws;                   ws += (size_t)N_NODES * DIM * 2;
    __half* abuf    = (__half*)ws;                   ws += (size_t)N_NODES * DIM * 2;

    const int blk = 256;
    int gCvt   = 6250;                           // 1.6M cvt chunks + 800k count
    int gBuild = 782;                            // 200000 int4 edge-quads
    int gAgg   = N_NODES / 32;                   // 3125 (32 nodes/block)
    int gTile  = (N_NODES + 63) / 64;            // 1563

    hipMemsetAsync(deg, 0, (size_t)(100352 + 4) * 4, stream);
    k_cvt_count<<<gCvt, blk, 0, stream>>>(x, xh, ei + N_EDGES, deg, rank);
    k_scan_fuse<<<99, blk, 0, stream>>>(deg, row_off, dinv, gcount,
                                        W3, b3, pW1, pb1, W3p, b3p);
    k_build<<<gBuild, blk, 0, stream>>>(ei, rank, row_off, dinv, edges);

    // ---- layer 1 ----
    k_aggregate<<<gAgg, blk, 0, stream>>>(xh, row_off, deg, edges, dinv, abuf);
    k_gemm_bn_h<<<gTile, blk, 0, stream>>>(abuf, W1, b1, bn1_g, bn1_b, bn1_m, bn1_v, hbuf);

    // ---- layer 2 ----
    k_aggregate<<<gAgg, blk, 0, stream>>>(hbuf, row_off, deg, edges, dinv, abuf);
    k_gemm_bn_h<<<gTile, blk, 0, stream>>>(abuf, W2, b2, bn2_g, bn2_b, bn2_m, bn2_v, hbuf);

    // ---- layer 3 + fused predictor ----
    k_aggregate<<<gAgg, blk, 0, stream>>>(hbuf, row_off, deg, edges, dinv, abuf);
    k_tail<<<gTile, blk, 0, stream>>>(abuf, W3p, b3p, pW2, pb2, out);
}